// Round 4
// baseline (463.982 us; speedup 1.0000x reference)
//
#include <hip/hip_runtime.h>

#define D 512
#define D4 (D / 4)
#define MAXC 256
#define FEPS 1e-12f
#define FBIG 3.0e38f
#define DROWS 8
#define TM 128   // class tile (rows), padded
#define BK 32    // k-chunk

__device__ __forceinline__ float wave_rsum(float v) {
#pragma unroll
    for (int o = 32; o > 0; o >>= 1) v += __shfl_down(v, o);
    return v;
}

__device__ __forceinline__ float wave_rsum_all(float v) {
#pragma unroll
    for (int o = 32; o > 0; o >>= 1) v += __shfl_xor(v, o);
    return v;
}

__device__ __forceinline__ float dot4(const float4 a, const float4 b) {
    return a.x * b.x + a.y * b.y + a.z * b.z + a.w * b.w;
}

// top_k tie-break: higher value wins; equal values -> smaller index wins
__device__ __forceinline__ bool better(float v1, int j1, float v2, int j2) {
    return (v1 > v2) || (v1 == v2 && (unsigned)j1 < (unsigned)j2);
}

// --- 1. row L2-normalize + a2[i] + fused class histogram ---
__global__ void k_normalize(const float* __restrict__ emb, const int* __restrict__ targets,
                            float* __restrict__ embn, float* __restrict__ a2,
                            int* __restrict__ ccount) {
    const int i = blockIdx.x;
    const int tid = threadIdx.x;  // 128 threads, float4 each
    __shared__ float red[2];
    const float4 x = ((const float4*)(emb + (size_t)i * D))[tid];
    float ss = x.x * x.x + x.y * x.y + x.z * x.z + x.w * x.w;
    ss = wave_rsum(ss);
    if ((tid & 63) == 0) red[tid >> 6] = ss;
    __syncthreads();
    const float tot = red[0] + red[1];
    const float inv = 1.0f / fmaxf(sqrtf(tot), FEPS);
    const float4 y = make_float4(x.x * inv, x.y * inv, x.z * inv, x.w * inv);
    ((float4*)(embn + (size_t)i * D))[tid] = y;
    float s2 = y.x * y.x + y.y * y.y + y.z * y.z + y.w * y.w;
    s2 = wave_rsum(s2);
    __syncthreads();
    if ((tid & 63) == 0) red[tid >> 6] = s2;
    __syncthreads();
    if (tid == 0) {
        a2[i] = red[0] + red[1];
        atomicAdd(&ccount[targets[i]], 1);
    }
}

// --- 2a. exclusive prefix over classes ---
__global__ void k_scan(const int* __restrict__ ccount, int* __restrict__ coff,
                       const int* __restrict__ ncls) {
    __shared__ int lc[MAXC];
    const int C = *ncls;
    for (int c = threadIdx.x; c < C; c += blockDim.x) lc[c] = ccount[c];
    __syncthreads();
    if (threadIdx.x == 0) {
        int s = 0;
        for (int c = 0; c < C; ++c) { coff[c] = s; s += lc[c]; }
        coff[C] = s;
    }
}

// --- 2b. deterministic (index-ordered) per-class row lists ---
__global__ void k_build(const int* __restrict__ t, const int* __restrict__ coff,
                        int* __restrict__ clist, int n, const int* __restrict__ ncls) {
    const int C = *ncls;
    __shared__ int wtot[4];
    for (int c = blockIdx.x; c < C; c += gridDim.x) {
        int base = coff[c];
        for (int start = 0; start < n; start += 256) {
            const int j = start + (int)threadIdx.x;
            const bool flag = (j < n) && (t[j] == c);
            const unsigned long long m = __ballot(flag);
            const int lane = threadIdx.x & 63;
            const int w = threadIdx.x >> 6;
            const int pre = __popcll(m & ((1ull << lane) - 1ull));
            if (lane == 0) wtot[w] = __popcll(m);
            __syncthreads();
            int woff = 0;
            for (int k = 0; k < w; ++k) woff += wtot[k];
            const int tot = wtot[0] + wtot[1] + wtot[2] + wtot[3];
            if (flag) clist[base + woff + pre] = j;
            base += tot;
            __syncthreads();
        }
    }
}

// --- 3. class centers (coalesced float4) + cc2[c] ---
__global__ void k_centers(const float* __restrict__ embn, const int* __restrict__ clist,
                          const int* __restrict__ coff, const int* __restrict__ ccount,
                          float* __restrict__ centers, float* __restrict__ cc2) {
    const int c = blockIdx.x;   // grid = MAXC
    const int tid = threadIdx.x;  // 128 = D4
    const int cnt = ccount[c];
    const int off = (cnt > 0) ? coff[c] : 0;
    float4 s = make_float4(0.f, 0.f, 0.f, 0.f);
    for (int m = 0; m < cnt; ++m) {
        const int j = clist[off + m];
        const float4 e = ((const float4*)(embn + (size_t)j * D))[tid];
        s.x += e.x; s.y += e.y; s.z += e.z; s.w += e.w;
    }
    const float inv = 1.0f / fmaxf((float)cnt, 1e-6f);
    const float4 v = make_float4(s.x * inv, s.y * inv, s.z * inv, s.w * inv);
    ((float4*)(centers + (size_t)c * D))[tid] = v;
    float ss = dot4(v, v);
    ss = wave_rsum(ss);
    __shared__ float red[2];
    if ((tid & 63) == 0) red[tid >> 6] = ss;
    __syncthreads();
    if (tid == 0) cc2[c] = red[0] + red[1];
}

// --- 4. d_neg_min: 8 rows per block, one thread per class ---
__global__ void k_dneg(const float* __restrict__ embn, const float* __restrict__ a2,
                       const int* __restrict__ t, const float* __restrict__ centers,
                       const float* __restrict__ cc2, float* __restrict__ dneg,
                       int n, const int* __restrict__ ncls) {
    const int C = *ncls;
    const int i0 = blockIdx.x * DROWS;
    __shared__ __align__(16) float lrow[DROWS][D];
    __shared__ float la2[DROWS];
    __shared__ int lt[DROWS];
    __shared__ float mins[DROWS][128];
#pragma unroll
    for (int r = 0; r < DROWS; ++r) {
        if (i0 + r < n)
            ((float4*)lrow[r])[threadIdx.x] =
                ((const float4*)(embn + (size_t)(i0 + r) * D))[threadIdx.x];
    }
    if (threadIdx.x < DROWS) {
        const int ii = i0 + (int)threadIdx.x;
        la2[threadIdx.x] = (ii < n) ? a2[ii] : 0.f;
        lt[threadIdx.x] = (ii < n) ? t[ii] : -1;
    }
    __syncthreads();
    const int c = threadIdx.x;
    float best[DROWS];
    if (c < C) {
        float acc[DROWS];
#pragma unroll
        for (int r = 0; r < DROWS; ++r) acc[r] = 0.f;
        const float4* cp = (const float4*)(centers + (size_t)c * D);
        for (int k = 0; k < D4; ++k) {
            const float4 cv = cp[k];
#pragma unroll
            for (int r = 0; r < DROWS; ++r) {
                const float4 ev = ((const float4*)lrow[r])[k];
                acc[r] += cv.x * ev.x + cv.y * ev.y + cv.z * ev.z + cv.w * ev.w;
            }
        }
        const float c2 = cc2[c];
#pragma unroll
        for (int r = 0; r < DROWS; ++r) {
            const float sq = la2[r] + c2 - 2.f * acc[r];
            float dv = sqrtf(fmaxf(sq, FEPS));
            if (lt[r] == c) dv = FBIG;
            best[r] = dv;
        }
    } else {
#pragma unroll
        for (int r = 0; r < DROWS; ++r) best[r] = FBIG;
    }
#pragma unroll
    for (int r = 0; r < DROWS; ++r) mins[r][threadIdx.x] = best[r];
    __syncthreads();
    for (int s = 64; s > 0; s >>= 1) {
        if (threadIdx.x < s) {
#pragma unroll
            for (int r = 0; r < DROWS; ++r)
                mins[r][threadIdx.x] = fminf(mins[r][threadIdx.x], mins[r][threadIdx.x + s]);
        }
        __syncthreads();
    }
    if (threadIdx.x < DROWS && i0 + (int)threadIdx.x < n)
        dneg[i0 + threadIdx.x] = mins[threadIdx.x][0];
}

// --- 5. per-class Gram GEMM + top-3 hardest positives + d_pos ---
// block = class; 256 threads as 16x16, each an 8x8 register tile of the
// 128x128 (padded) Gram. K staged in LDS (BK=32) with XOR float4-slot swizzle.
__global__ __launch_bounds__(256) void k_pos(
    const float* __restrict__ embn, const float* __restrict__ a2,
    const int* __restrict__ clist, const int* __restrict__ coff,
    const int* __restrict__ ccount, float* __restrict__ dpos,
    float* __restrict__ dvalid) {
    const int c = blockIdx.x;
    const int m = ccount[c];
    if (m == 0) return;
    const int off = coff[c];
    const int tid = threadIdx.x;
    const int tx = tid & 15;   // j-group
    const int ty = tid >> 4;   // i-group
    const int lane = tid & 63;
    const int wav = tid >> 6;

    __shared__ __align__(16) float As[TM * BK];   // 16 KB (swizzled float4 slots)
    __shared__ __align__(16) float Bs[TM * BK];   // 16 KB
    __shared__ float a2i_s[TM], a2j_s[TM];
    __shared__ int iglob_s[TM], jglob_s[TM];
    __shared__ float candv[TM * 16 * 3];          // 24 KB
    __shared__ int candj[TM * 16 * 3];            // 24 KB
    __shared__ int rtopj_s[TM][3];

    for (int it = 0; it < m; it += TM) {
        // stage i-tile metadata
        if (tid < TM) {
            const int gr = it + tid;
            const int gi = (gr < m) ? clist[off + gr] : -1;
            iglob_s[tid] = gi;
            a2i_s[tid] = (gi >= 0) ? a2[gi] : 0.f;
        }
        // running top3 (registers of the 128 merge threads)
        float rv0 = -FBIG, rv1 = -FBIG, rv2 = -FBIG;
        int rj0 = -1, rj1 = -1, rj2 = -1;

        for (int jt = 0; jt < m; jt += TM) {
            if (tid < TM) {
                const int gr = jt + tid;
                const int gj = (gr < m) ? clist[off + gr] : -1;
                jglob_s[tid] = gj;
                a2j_s[tid] = (gj >= 0) ? a2[gj] : 0.f;
            }
            float acc[8][8];
#pragma unroll
            for (int u = 0; u < 8; ++u)
#pragma unroll
                for (int v = 0; v < 8; ++v) acc[u][v] = 0.f;

            for (int kc = 0; kc < D; kc += BK) {
                __syncthreads();  // previous chunk reads done (and metadata staged on kc==0)
                const int kc4 = kc >> 2;
#pragma unroll
                for (int s = 0; s < 4; ++s) {
                    const int u = s * 256 + tid;       // 0..1023 float4 slots
                    const int r = u >> 3;              // row 0..127
                    const int c8 = u & 7;              // float4 slot within BK
                    const int sw = c8 ^ ((r >> 3) & 7);
                    const int gi = iglob_s[r];
                    float4 va = make_float4(0.f, 0.f, 0.f, 0.f);
                    if (gi >= 0) va = ((const float4*)(embn + (size_t)gi * D))[kc4 + c8];
                    ((float4*)As)[r * 8 + sw] = va;
                    const int gj = jglob_s[r];
                    float4 vb = make_float4(0.f, 0.f, 0.f, 0.f);
                    if (gj >= 0) vb = ((const float4*)(embn + (size_t)gj * D))[kc4 + c8];
                    ((float4*)Bs)[r * 8 + sw] = vb;
                }
                __syncthreads();
#pragma unroll
                for (int k4 = 0; k4 < 8; ++k4) {
                    float4 a[8], b[8];
#pragma unroll
                    for (int u = 0; u < 8; ++u)
                        a[u] = ((const float4*)As)[(ty * 8 + u) * 8 + (k4 ^ (ty & 7))];
#pragma unroll
                    for (int v = 0; v < 8; ++v)
                        b[v] = ((const float4*)Bs)[(tx * 8 + v) * 8 + (k4 ^ (tx & 7))];
#pragma unroll
                    for (int u = 0; u < 8; ++u)
#pragma unroll
                        for (int v = 0; v < 8; ++v)
                            acc[u][v] += dot4(a[u], b[v]);
                }
            }
            __syncthreads();

            // per-thread top3 per owned i-row over its 8 j's -> candidates
#pragma unroll
            for (int u = 0; u < 8; ++u) {
                const int iloc = ty * 8 + u;
                const int ig = iglob_s[iloc];
                float t0 = -FBIG, t1 = -FBIG, t2 = -FBIG;
                int x0 = -1, x1 = -1, x2 = -1;
                if ((it + iloc) < m) {
                    const float a2i = a2i_s[iloc];
#pragma unroll
                    for (int v = 0; v < 8; ++v) {
                        const int jloc = tx * 8 + v;
                        const int jg = jglob_s[jloc];
                        if ((jt + jloc) < m && jg != ig) {
                            const float sq = a2i + a2j_s[jloc] - 2.f * acc[u][v];
                            if (sq > t0)      { t2 = t1; x2 = x1; t1 = t0; x1 = x0; t0 = sq; x0 = jg; }
                            else if (sq > t1) { t2 = t1; x2 = x1; t1 = sq; x1 = jg; }
                            else if (sq > t2) { t2 = sq; x2 = jg; }
                        }
                    }
                }
                const int base = (iloc * 16 + tx) * 3;
                candv[base] = t0; candv[base + 1] = t1; candv[base + 2] = t2;
                candj[base] = x0; candj[base + 1] = x1; candj[base + 2] = x2;
            }
            __syncthreads();

            // merge 48 candidates per row into running top3 (128 threads)
            if (tid < TM) {
                for (int g = 0; g < 16; ++g) {
#pragma unroll
                    for (int s = 0; s < 3; ++s) {
                        const int base = (tid * 16 + g) * 3 + s;
                        const float v = candv[base];
                        const int j = candj[base];
                        if (j >= 0) {
                            if (better(v, j, rv0, rj0)) {
                                rv2 = rv1; rj2 = rj1; rv1 = rv0; rj1 = rj0; rv0 = v; rj0 = j;
                            } else if (better(v, j, rv1, rj1)) {
                                rv2 = rv1; rj2 = rj1; rv1 = v; rj1 = j;
                            } else if (better(v, j, rv2, rj2)) {
                                rv2 = v; rj2 = j;
                            }
                        }
                    }
                }
            }
        }
        __syncthreads();
        if (tid < TM) {
            rtopj_s[tid][0] = rj0; rtopj_s[tid][1] = rj1; rtopj_s[tid][2] = rj2;
        }
        __syncthreads();

        // d_pos: one wave per row (4 waves round-robin)
        for (int rl = wav; rl < TM; rl += 4) {
            if (it + rl >= m) continue;
            const int i = iglob_s[rl];
            const int j0 = rtopj_s[rl][0], j1 = rtopj_s[rl][1], j2 = rtopj_s[rl][2];
            const int nw = (j0 >= 0) + (j1 >= 0) + (j2 >= 0);
            if (nw > 0) {
                const int jA = j0;
                const int jB = (j1 >= 0) ? j1 : jA;
                const int jC = (j2 >= 0) ? j2 : jB;
                const float4* pi = (const float4*)(embn + (size_t)i * D);
                const float4* r0 = (const float4*)(embn + (size_t)jA * D);
                const float4* r1 = (const float4*)(embn + (size_t)jB * D);
                const float4* r2 = (const float4*)(embn + (size_t)jC * D);
                float accp = 0.f;
#pragma unroll
                for (int s = 0; s < 2; ++s) {
                    const int k4 = lane + 64 * s;
                    const float4 a = pi[k4];
                    const float4 v0 = r0[k4], v1 = r1[k4], v2 = r2[k4];
                    const float cx = (v0.x + v1.x + v2.x) * (1.f / 3.f);
                    const float cy = (v0.y + v1.y + v2.y) * (1.f / 3.f);
                    const float cz = (v0.z + v1.z + v2.z) * (1.f / 3.f);
                    const float cw = (v0.w + v1.w + v2.w) * (1.f / 3.f);
                    const float dx = a.x - cx, dy = a.y - cy, dz = a.z - cz, dw = a.w - cw;
                    accp += dx * dx + dy * dy + dz * dz + dw * dw;
                }
                accp = wave_rsum_all(accp);
                if (lane == 0) { dpos[i] = sqrtf(fmaxf(accp, FEPS)); dvalid[i] = 1.f; }
            } else if (lane == 0) {
                dpos[i] = 0.f; dvalid[i] = 0.f;
            }
        }
        __syncthreads();  // protect metadata arrays before next i-tile
    }
}

// --- 6. stable softplus + masked mean ---
__global__ void k_loss(const float* __restrict__ dpos, const float* __restrict__ dneg,
                       const float* __restrict__ dvalid, float* __restrict__ accum, int n) {
    const int i = blockIdx.x * blockDim.x + threadIdx.x;
    float l = 0.f, v = 0.f;
    if (i < n) {
        v = dvalid[i];
        const float x = dpos[i] - dneg[i];
        const float sp = fmaxf(x, 0.f) + log1pf(expf(-fabsf(x)));
        l = sp * v;
    }
    l = wave_rsum(l);
    v = wave_rsum(v);
    __shared__ float wl[4], wv[4];
    const int lane = threadIdx.x & 63, w = threadIdx.x >> 6;
    if (lane == 0) { wl[w] = l; wv[w] = v; }
    __syncthreads();
    if (threadIdx.x == 0) {
        atomicAdd(&accum[0], wl[0] + wl[1] + wl[2] + wl[3]);
        atomicAdd(&accum[1], wv[0] + wv[1] + wv[2] + wv[3]);
    }
}

__global__ void k_final(const float* __restrict__ accum, float* __restrict__ out) {
    out[0] = accum[0] / fmaxf(accum[1], 1.0f);
}

extern "C" void kernel_launch(void* const* d_in, const int* in_sizes, int n_in,
                              void* d_out, int out_size, void* d_ws, size_t ws_size,
                              hipStream_t stream) {
    const float* emb = (const float*)d_in[0];
    const int* targets = (const int*)d_in[1];
    const int* ncls = (const int*)d_in[2];
    const int n = in_sizes[1];  // 8192

    float* fp = (float*)d_ws;
    float* embn = fp;    fp += (size_t)n * D;
    float* a2 = fp;      fp += n;
    float* centers = fp; fp += (size_t)MAXC * D;
    float* cc2 = fp;     fp += MAXC;
    float* dneg = fp;    fp += n;
    float* dpos = fp;    fp += n;
    float* dvalid = fp;  fp += n;
    float* accum = fp;   fp += 2;
    int* ccount = (int*)fp; fp += MAXC;
    int* coff = (int*)fp;   fp += MAXC + 1;
    int* clist = (int*)fp;  fp += n;

    hipMemsetAsync(ccount, 0, MAXC * sizeof(int), stream);
    hipMemsetAsync(accum, 0, 2 * sizeof(float), stream);

    k_normalize<<<n, 128, 0, stream>>>(emb, targets, embn, a2, ccount);
    k_scan<<<1, 256, 0, stream>>>(ccount, coff, ncls);
    k_build<<<128, 256, 0, stream>>>(targets, coff, clist, n, ncls);
    k_centers<<<MAXC, 128, 0, stream>>>(embn, clist, coff, ccount, centers, cc2);
    k_dneg<<<(n + DROWS - 1) / DROWS, 128, 0, stream>>>(embn, a2, targets, centers, cc2, dneg, n, ncls);
    k_pos<<<MAXC, 256, 0, stream>>>(embn, a2, clist, coff, ccount, dpos, dvalid);
    k_loss<<<(n + 255) / 256, 256, 0, stream>>>(dpos, dneg, dvalid, accum, n);
    k_final<<<1, 1, 0, stream>>>(accum, (float*)d_out);
}

// Round 5
// 342.484 us; speedup vs baseline: 1.3548x; 1.3548x over previous
//
#include <hip/hip_runtime.h>

#define D 512
#define D4 (D / 4)
#define MAXC 256
#define FEPS 1e-12f
#define FBIG 3.0e38f
#define DROWS 8
#define TI 32    // i-rows per k_pos block
#define TJ 128   // j-cols per k_pos pass

__device__ __forceinline__ float wave_rsum(float v) {
#pragma unroll
    for (int o = 32; o > 0; o >>= 1) v += __shfl_down(v, o);
    return v;
}

__device__ __forceinline__ float wave_rsum_all(float v) {
#pragma unroll
    for (int o = 32; o > 0; o >>= 1) v += __shfl_xor(v, o);
    return v;
}

__device__ __forceinline__ float dot4(const float4 a, const float4 b) {
    return a.x * b.x + a.y * b.y + a.z * b.z + a.w * b.w;
}

// top_k tie-break: higher value wins; equal values -> smaller global index wins
__device__ __forceinline__ bool better(float v1, int j1, float v2, int j2) {
    return (v1 > v2) || (v1 == v2 && (unsigned)j1 < (unsigned)j2);
}

__device__ __forceinline__ void ins3(float v, int j, float& t0, float& t1, float& t2,
                                     int& x0, int& x1, int& x2) {
    if (j < 0) return;
    if (better(v, j, t0, x0)) { t2 = t1; x2 = x1; t1 = t0; x1 = x0; t0 = v; x0 = j; }
    else if (better(v, j, t1, x1)) { t2 = t1; x2 = x1; t1 = v; x1 = j; }
    else if (better(v, j, t2, x2)) { t2 = v; x2 = j; }
}

// --- 1. row L2-normalize + a2[i] + fused class histogram ---
__global__ void k_normalize(const float* __restrict__ emb, const int* __restrict__ targets,
                            float* __restrict__ embn, float* __restrict__ a2,
                            int* __restrict__ ccount) {
    const int i = blockIdx.x;
    const int tid = threadIdx.x;  // 128 threads, float4 each
    __shared__ float red[2];
    const float4 x = ((const float4*)(emb + (size_t)i * D))[tid];
    float ss = x.x * x.x + x.y * x.y + x.z * x.z + x.w * x.w;
    ss = wave_rsum(ss);
    if ((tid & 63) == 0) red[tid >> 6] = ss;
    __syncthreads();
    const float tot = red[0] + red[1];
    const float inv = 1.0f / fmaxf(sqrtf(tot), FEPS);
    const float4 y = make_float4(x.x * inv, x.y * inv, x.z * inv, x.w * inv);
    ((float4*)(embn + (size_t)i * D))[tid] = y;
    float s2 = y.x * y.x + y.y * y.y + y.z * y.z + y.w * y.w;
    s2 = wave_rsum(s2);
    __syncthreads();
    if ((tid & 63) == 0) red[tid >> 6] = s2;
    __syncthreads();
    if (tid == 0) {
        a2[i] = red[0] + red[1];
        atomicAdd(&ccount[targets[i]], 1);
    }
}

// --- 2a. exclusive prefix over classes ---
__global__ void k_scan(const int* __restrict__ ccount, int* __restrict__ coff,
                       const int* __restrict__ ncls) {
    __shared__ int lc[MAXC];
    const int C = *ncls;
    for (int c = threadIdx.x; c < C; c += blockDim.x) lc[c] = ccount[c];
    __syncthreads();
    if (threadIdx.x == 0) {
        int s = 0;
        for (int c = 0; c < C; ++c) { coff[c] = s; s += lc[c]; }
        coff[C] = s;
    }
}

// --- 2b. deterministic (index-ordered) per-class row lists ---
__global__ void k_build(const int* __restrict__ t, const int* __restrict__ coff,
                        int* __restrict__ clist, int n, const int* __restrict__ ncls) {
    const int C = *ncls;
    __shared__ int wtot[4];
    for (int c = blockIdx.x; c < C; c += gridDim.x) {
        int base = coff[c];
        for (int start = 0; start < n; start += 256) {
            const int j = start + (int)threadIdx.x;
            const bool flag = (j < n) && (t[j] == c);
            const unsigned long long m = __ballot(flag);
            const int lane = threadIdx.x & 63;
            const int w = threadIdx.x >> 6;
            const int pre = __popcll(m & ((1ull << lane) - 1ull));
            if (lane == 0) wtot[w] = __popcll(m);
            __syncthreads();
            int woff = 0;
            for (int k = 0; k < w; ++k) woff += wtot[k];
            const int tot = wtot[0] + wtot[1] + wtot[2] + wtot[3];
            if (flag) clist[base + woff + pre] = j;
            base += tot;
            __syncthreads();
        }
    }
}

// --- 3. class centers: grid (4 d-chunks x MAXC), 128 threads ---
__global__ void k_centers(const float* __restrict__ embn, const int* __restrict__ clist,
                          const int* __restrict__ coff, const int* __restrict__ ccount,
                          float* __restrict__ centers) {
    const int c = blockIdx.y;
    const int dchunk = blockIdx.x;      // 32 float4 slots each
    const int cnt = ccount[c];
    const int off = (cnt > 0) ? coff[c] : 0;
    const int tid = threadIdx.x;        // 128
    const int slot = tid & 31;
    const int rg = tid >> 5;            // 0..3
    float4 s = make_float4(0.f, 0.f, 0.f, 0.f);
    for (int mi = rg; mi < cnt; mi += 4) {
        const int j = clist[off + mi];
        const float4 e = ((const float4*)(embn + (size_t)j * D))[dchunk * 32 + slot];
        s.x += e.x; s.y += e.y; s.z += e.z; s.w += e.w;
    }
    __shared__ float4 part[4][32];
    part[rg][slot] = s;
    __syncthreads();
    if (rg == 0) {
        const float4 p0 = part[0][slot], p1 = part[1][slot], p2 = part[2][slot], p3 = part[3][slot];
        const float inv = 1.0f / fmaxf((float)cnt, 1e-6f);
        const float4 v = make_float4((p0.x + p1.x + p2.x + p3.x) * inv,
                                     (p0.y + p1.y + p2.y + p3.y) * inv,
                                     (p0.z + p1.z + p2.z + p3.z) * inv,
                                     (p0.w + p1.w + p2.w + p3.w) * inv);
        ((float4*)(centers + (size_t)c * D))[dchunk * 32 + slot] = v;
    }
}

// --- 4. d_neg_min: 8 rows per block, one thread per class (cc2 inline) ---
__global__ void k_dneg(const float* __restrict__ embn, const float* __restrict__ a2,
                       const int* __restrict__ t, const float* __restrict__ centers,
                       float* __restrict__ dneg, int n, const int* __restrict__ ncls) {
    const int C = *ncls;
    const int i0 = blockIdx.x * DROWS;
    __shared__ __align__(16) float lrow[DROWS][D];
    __shared__ float la2[DROWS];
    __shared__ int lt[DROWS];
    __shared__ float mins[DROWS][128];
#pragma unroll
    for (int r = 0; r < DROWS; ++r) {
        if (i0 + r < n)
            ((float4*)lrow[r])[threadIdx.x] =
                ((const float4*)(embn + (size_t)(i0 + r) * D))[threadIdx.x];
    }
    if (threadIdx.x < DROWS) {
        const int ii = i0 + (int)threadIdx.x;
        la2[threadIdx.x] = (ii < n) ? a2[ii] : 0.f;
        lt[threadIdx.x] = (ii < n) ? t[ii] : -1;
    }
    __syncthreads();
    const int c = threadIdx.x;
    float best[DROWS];
    if (c < C) {
        float acc[DROWS];
#pragma unroll
        for (int r = 0; r < DROWS; ++r) acc[r] = 0.f;
        float c2acc = 0.f;
        const float4* cp = (const float4*)(centers + (size_t)c * D);
        for (int k = 0; k < D4; ++k) {
            const float4 cv = cp[k];
            c2acc += dot4(cv, cv);
#pragma unroll
            for (int r = 0; r < DROWS; ++r) {
                const float4 ev = ((const float4*)lrow[r])[k];
                acc[r] += cv.x * ev.x + cv.y * ev.y + cv.z * ev.z + cv.w * ev.w;
            }
        }
#pragma unroll
        for (int r = 0; r < DROWS; ++r) {
            const float sq = la2[r] + c2acc - 2.f * acc[r];
            float dv = sqrtf(fmaxf(sq, FEPS));
            if (lt[r] == c) dv = FBIG;
            best[r] = dv;
        }
    } else {
#pragma unroll
        for (int r = 0; r < DROWS; ++r) best[r] = FBIG;
    }
#pragma unroll
    for (int r = 0; r < DROWS; ++r) mins[r][threadIdx.x] = best[r];
    __syncthreads();
    for (int s = 64; s > 0; s >>= 1) {
        if (threadIdx.x < s) {
#pragma unroll
            for (int r = 0; r < DROWS; ++r)
                mins[r][threadIdx.x] = fminf(mins[r][threadIdx.x], mins[r][threadIdx.x + s]);
        }
        __syncthreads();
    }
    if (threadIdx.x < DROWS && i0 + (int)threadIdx.x < n)
        dneg[i0 + threadIdx.x] = mins[threadIdx.x][0];
}

// --- 5. per-class Gram + top-3 hardest positives + d_pos ---
// grid (4 i-tiles x class), 256 threads as 8(ty) x 32(tx), 4x4 register tile.
// thread's i-rows: ty+8u (u<4); j-cols: tx+32v (v<4). LDS: transposed k-chunk tiles.
__global__ __launch_bounds__(256, 4) void k_pos(
    const float* __restrict__ embn, const float* __restrict__ a2,
    const int* __restrict__ clist, const int* __restrict__ coff,
    const int* __restrict__ ccount, float* __restrict__ dpos,
    float* __restrict__ dvalid) {
    const int c = blockIdx.y;
    const int m = ccount[c];
    const int it0 = blockIdx.x * TI;
    if (m == 0 || it0 >= m) return;  // block-uniform
    const int off = coff[c];
    const int tid = threadIdx.x;
    const int tx = tid & 31;
    const int ty = tid >> 5;
    const int lane = tid & 63;
    const int wav = tid >> 6;

    __shared__ float4 At[8][TI];    // 4 KB per k-chunk (slot-major, transposed)
    __shared__ float4 Bt[8][TJ];    // 16 KB
    __shared__ int ig_s[TI];
    __shared__ float a2i_s[TI];
    __shared__ int jg_s[TJ];
    __shared__ float a2j_s[TJ];
    __shared__ int topj_s[TI][3];

    if (tid < TI) {
        const int gr = it0 + tid;
        const int gi = (gr < m) ? clist[off + gr] : -1;
        ig_s[tid] = gi;
        a2i_s[tid] = (gi >= 0) ? a2[gi] : 0.f;
    }

    float rv0[4], rv1[4], rv2[4];
    int rj0[4], rj1[4], rj2[4];
#pragma unroll
    for (int u = 0; u < 4; ++u) {
        rv0[u] = rv1[u] = rv2[u] = -FBIG;
        rj0[u] = rj1[u] = rj2[u] = -1;
    }

    for (int jb = 0; jb < m; jb += TJ) {
        __syncthreads();  // previous pass done with jg_s/a2j_s
        if (tid < TJ) {
            const int gr = jb + tid;
            const int gj = (gr < m) ? clist[off + gr] : -1;
            jg_s[tid] = gj;
            a2j_s[tid] = (gj >= 0) ? a2[gj] : 0.f;
        }
        float acc[4][4];
#pragma unroll
        for (int u = 0; u < 4; ++u)
#pragma unroll
            for (int v = 0; v < 4; ++v) acc[u][v] = 0.f;

        for (int kc4 = 0; kc4 < D4; kc4 += 8) {  // 16 k-chunks of 32 floats
            __syncthreads();  // previous chunk's compute done; metadata staged
            {   // stage A: 256 threads -> 32 rows x 8 slots
                const int arow = tid & 31, slot = tid >> 5;
                const int gi = ig_s[arow];
                float4 va = make_float4(0.f, 0.f, 0.f, 0.f);
                if (gi >= 0) va = ((const float4*)(embn + (size_t)gi * D))[kc4 + slot];
                At[slot][arow] = va;
            }
#pragma unroll
            for (int s = 0; s < 4; ++s) {  // stage B: 128 rows x 8 slots
                const int jrow = tid & 127;
                const int slot = (tid >> 7) + 2 * s;
                const int gj = jg_s[jrow];
                float4 vb = make_float4(0.f, 0.f, 0.f, 0.f);
                if (gj >= 0) vb = ((const float4*)(embn + (size_t)gj * D))[kc4 + slot];
                Bt[slot][jrow] = vb;
            }
            __syncthreads();
#pragma unroll
            for (int k4 = 0; k4 < 8; ++k4) {
                float4 a[4], b[4];
#pragma unroll
                for (int u = 0; u < 4; ++u) a[u] = At[k4][ty + 8 * u];     // broadcast
#pragma unroll
                for (int v = 0; v < 4; ++v) b[v] = Bt[k4][tx + 32 * v];    // contiguous
#pragma unroll
                for (int u = 0; u < 4; ++u)
#pragma unroll
                    for (int v = 0; v < 4; ++v) acc[u][v] += dot4(a[u], b[v]);
            }
        }
        // selection: per-thread running top3 per owned i-row
#pragma unroll
        for (int u = 0; u < 4; ++u) {
            const int iloc = ty + 8 * u;
            const int ig = ig_s[iloc];
            if (ig < 0) continue;
            const float a2i = a2i_s[iloc];
#pragma unroll
            for (int v = 0; v < 4; ++v) {
                const int jloc = tx + 32 * v;
                const int jg = jg_s[jloc];
                if (jg >= 0 && jg != ig) {
                    const float sq = a2i + a2j_s[jloc] - 2.f * acc[u][v];
                    ins3(sq, jg, rv0[u], rv1[u], rv2[u], rj0[u], rj1[u], rj2[u]);
                }
            }
        }
    }

    // butterfly merge across the 32 tx lanes (stays within half-wave)
#pragma unroll
    for (int o = 16; o > 0; o >>= 1) {
#pragma unroll
        for (int u = 0; u < 4; ++u) {
            const float ov0 = __shfl_xor(rv0[u], o); const int oj0 = __shfl_xor(rj0[u], o);
            const float ov1 = __shfl_xor(rv1[u], o); const int oj1 = __shfl_xor(rj1[u], o);
            const float ov2 = __shfl_xor(rv2[u], o); const int oj2 = __shfl_xor(rj2[u], o);
            ins3(ov0, oj0, rv0[u], rv1[u], rv2[u], rj0[u], rj1[u], rj2[u]);
            ins3(ov1, oj1, rv0[u], rv1[u], rv2[u], rj0[u], rj1[u], rj2[u]);
            ins3(ov2, oj2, rv0[u], rv1[u], rv2[u], rj0[u], rj1[u], rj2[u]);
        }
    }
    if (tx == 0) {
#pragma unroll
        for (int u = 0; u < 4; ++u) {
            const int iloc = ty + 8 * u;
            topj_s[iloc][0] = rj0[u]; topj_s[iloc][1] = rj1[u]; topj_s[iloc][2] = rj2[u];
        }
    }
    __syncthreads();

    // d_pos tail: 4 waves round-robin the 32 rows
    for (int rl = wav; rl < TI; rl += 4) {
        if (it0 + rl >= m) continue;
        const int i = ig_s[rl];
        const int j0 = topj_s[rl][0], j1 = topj_s[rl][1], j2 = topj_s[rl][2];
        const int nw = (j0 >= 0) + (j1 >= 0) + (j2 >= 0);
        if (nw > 0) {
            const int jA = j0;
            const int jB = (j1 >= 0) ? j1 : jA;
            const int jC = (j2 >= 0) ? j2 : jB;
            const float4* pi = (const float4*)(embn + (size_t)i * D);
            const float4* r0 = (const float4*)(embn + (size_t)jA * D);
            const float4* r1 = (const float4*)(embn + (size_t)jB * D);
            const float4* r2 = (const float4*)(embn + (size_t)jC * D);
            float accp = 0.f;
#pragma unroll
            for (int s = 0; s < 2; ++s) {
                const int k4 = lane + 64 * s;
                const float4 a = pi[k4];
                const float4 v0 = r0[k4], v1 = r1[k4], v2 = r2[k4];
                const float cx = (v0.x + v1.x + v2.x) * (1.f / 3.f);
                const float cy = (v0.y + v1.y + v2.y) * (1.f / 3.f);
                const float cz = (v0.z + v1.z + v2.z) * (1.f / 3.f);
                const float cw = (v0.w + v1.w + v2.w) * (1.f / 3.f);
                const float dx = a.x - cx, dy = a.y - cy, dz = a.z - cz, dw = a.w - cw;
                accp += dx * dx + dy * dy + dz * dz + dw * dw;
            }
            accp = wave_rsum_all(accp);
            if (lane == 0) { dpos[i] = sqrtf(fmaxf(accp, FEPS)); dvalid[i] = 1.f; }
        } else if (lane == 0) {
            dpos[i] = 0.f; dvalid[i] = 0.f;
        }
    }
}

// --- 6. stable softplus + masked mean ---
__global__ void k_loss(const float* __restrict__ dpos, const float* __restrict__ dneg,
                       const float* __restrict__ dvalid, float* __restrict__ accum, int n) {
    const int i = blockIdx.x * blockDim.x + threadIdx.x;
    float l = 0.f, v = 0.f;
    if (i < n) {
        v = dvalid[i];
        const float x = dpos[i] - dneg[i];
        const float sp = fmaxf(x, 0.f) + log1pf(expf(-fabsf(x)));
        l = sp * v;
    }
    l = wave_rsum(l);
    v = wave_rsum(v);
    __shared__ float wl[4], wv[4];
    const int lane = threadIdx.x & 63, w = threadIdx.x >> 6;
    if (lane == 0) { wl[w] = l; wv[w] = v; }
    __syncthreads();
    if (threadIdx.x == 0) {
        atomicAdd(&accum[0], wl[0] + wl[1] + wl[2] + wl[3]);
        atomicAdd(&accum[1], wv[0] + wv[1] + wv[2] + wv[3]);
    }
}

__global__ void k_final(const float* __restrict__ accum, float* __restrict__ out) {
    out[0] = accum[0] / fmaxf(accum[1], 1.0f);
}

extern "C" void kernel_launch(void* const* d_in, const int* in_sizes, int n_in,
                              void* d_out, int out_size, void* d_ws, size_t ws_size,
                              hipStream_t stream) {
    const float* emb = (const float*)d_in[0];
    const int* targets = (const int*)d_in[1];
    const int* ncls = (const int*)d_in[2];
    const int n = in_sizes[1];  // 8192

    float* fp = (float*)d_ws;
    float* embn = fp;    fp += (size_t)n * D;
    float* a2 = fp;      fp += n;
    float* centers = fp; fp += (size_t)MAXC * D;
    float* dneg = fp;    fp += n;
    float* dpos = fp;    fp += n;
    float* dvalid = fp;  fp += n;
    float* accum = fp;   fp += 2;
    int* ccount = (int*)fp; fp += MAXC;
    int* coff = (int*)fp;   fp += MAXC + 1;
    int* clist = (int*)fp;  fp += n;

    hipMemsetAsync(ccount, 0, MAXC * sizeof(int), stream);
    hipMemsetAsync(accum, 0, 2 * sizeof(float), stream);

    k_normalize<<<n, 128, 0, stream>>>(emb, targets, embn, a2, ccount);
    k_scan<<<1, 256, 0, stream>>>(ccount, coff, ncls);
    k_build<<<128, 256, 0, stream>>>(targets, coff, clist, n, ncls);
    k_centers<<<dim3(4, MAXC), 128, 0, stream>>>(embn, clist, coff, ccount, centers);
    k_dneg<<<(n + DROWS - 1) / DROWS, 128, 0, stream>>>(embn, a2, targets, centers, dneg, n, ncls);
    k_pos<<<dim3(4, MAXC), 256, 0, stream>>>(embn, a2, clist, coff, ccount, dpos, dvalid);
    k_loss<<<(n + 255) / 256, 256, 0, stream>>>(dpos, dneg, dvalid, accum, n);
    k_final<<<1, 1, 0, stream>>>(accum, (float*)d_out);
}

// Round 6
// 225.229 us; speedup vs baseline: 2.0600x; 1.5206x over previous
//
#include <hip/hip_runtime.h>

#define D 512
#define D4 (D / 4)
#define MAXC 256
#define FEPS 1e-12f
#define FBIG 3.0e38f
#define DROWS 8
#define TI 32    // i-rows per k_pos block
#define TJ 128   // j-cols per k_pos pass

__device__ __forceinline__ float wave_rsum(float v) {
#pragma unroll
    for (int o = 32; o > 0; o >>= 1) v += __shfl_down(v, o);
    return v;
}

__device__ __forceinline__ float wave_rsum_all(float v) {
#pragma unroll
    for (int o = 32; o > 0; o >>= 1) v += __shfl_xor(v, o);
    return v;
}

__device__ __forceinline__ float dot4(const float4 a, const float4 b) {
    return a.x * b.x + a.y * b.y + a.z * b.z + a.w * b.w;
}

// top_k tie-break: higher value wins; equal values -> smaller global index wins
__device__ __forceinline__ bool better(float v1, int j1, float v2, int j2) {
    return (v1 > v2) || (v1 == v2 && (unsigned)j1 < (unsigned)j2);
}

__device__ __forceinline__ void ins3(float v, int j, float& t0, float& t1, float& t2,
                                     int& x0, int& x1, int& x2) {
    if (j < 0) return;
    if (better(v, j, t0, x0)) { t2 = t1; x2 = x1; t1 = t0; x1 = x0; t0 = v; x0 = j; }
    else if (better(v, j, t1, x1)) { t2 = t1; x2 = x1; t1 = v; x1 = j; }
    else if (better(v, j, t2, x2)) { t2 = v; x2 = j; }
}

// --- 1. row L2-normalize + a2[i] + fused class histogram ---
__global__ void k_normalize(const float* __restrict__ emb, const int* __restrict__ targets,
                            float* __restrict__ embn, float* __restrict__ a2,
                            int* __restrict__ ccount) {
    const int i = blockIdx.x;
    const int tid = threadIdx.x;  // 128 threads, float4 each
    __shared__ float red[2];
    const float4 x = ((const float4*)(emb + (size_t)i * D))[tid];
    float ss = x.x * x.x + x.y * x.y + x.z * x.z + x.w * x.w;
    ss = wave_rsum(ss);
    if ((tid & 63) == 0) red[tid >> 6] = ss;
    __syncthreads();
    const float tot = red[0] + red[1];
    const float inv = 1.0f / fmaxf(sqrtf(tot), FEPS);
    const float4 y = make_float4(x.x * inv, x.y * inv, x.z * inv, x.w * inv);
    ((float4*)(embn + (size_t)i * D))[tid] = y;
    float s2 = y.x * y.x + y.y * y.y + y.z * y.z + y.w * y.w;
    s2 = wave_rsum(s2);
    __syncthreads();
    if ((tid & 63) == 0) red[tid >> 6] = s2;
    __syncthreads();
    if (tid == 0) {
        a2[i] = red[0] + red[1];
        atomicAdd(&ccount[targets[i]], 1);
    }
}

// --- 2. per-class offset (in-block prefix reduce) + deterministic row lists ---
__global__ void k_build(const int* __restrict__ t, const int* __restrict__ ccount,
                        int* __restrict__ coff, int* __restrict__ clist, int n,
                        const int* __restrict__ ncls) {
    const int C = *ncls;
    const int c = blockIdx.x;  // grid = MAXC
    if (c >= C) return;
    __shared__ int pref[256];
    pref[threadIdx.x] = ((int)threadIdx.x < c) ? ccount[threadIdx.x] : 0;
    __syncthreads();
    for (int s = 128; s > 0; s >>= 1) {
        if (threadIdx.x < s) pref[threadIdx.x] += pref[threadIdx.x + s];
        __syncthreads();
    }
    int base = pref[0];
    if (threadIdx.x == 0) coff[c] = base;
    __shared__ int wtot[4];
    for (int start = 0; start < n; start += 256) {
        const int j = start + (int)threadIdx.x;
        const bool flag = (j < n) && (t[j] == c);
        const unsigned long long m = __ballot(flag);
        const int lane = threadIdx.x & 63;
        const int w = threadIdx.x >> 6;
        const int pre = __popcll(m & ((1ull << lane) - 1ull));
        if (lane == 0) wtot[w] = __popcll(m);
        __syncthreads();
        int woff = 0;
        for (int k = 0; k < w; ++k) woff += wtot[k];
        const int tot = wtot[0] + wtot[1] + wtot[2] + wtot[3];
        if (flag) clist[base + woff + pre] = j;
        base += tot;
        __syncthreads();
    }
}

// --- 3. class centers: grid (4 d-chunks x MAXC), 128 threads ---
__global__ void k_centers(const float* __restrict__ embn, const int* __restrict__ clist,
                          const int* __restrict__ coff, const int* __restrict__ ccount,
                          float* __restrict__ centers) {
    const int c = blockIdx.y;
    const int dchunk = blockIdx.x;      // 32 float4 slots each
    const int cnt = ccount[c];
    const int off = (cnt > 0) ? coff[c] : 0;
    const int tid = threadIdx.x;        // 128
    const int slot = tid & 31;
    const int rg = tid >> 5;            // 0..3
    float4 s = make_float4(0.f, 0.f, 0.f, 0.f);
    for (int mi = rg; mi < cnt; mi += 4) {
        const int j = clist[off + mi];
        const float4 e = ((const float4*)(embn + (size_t)j * D))[dchunk * 32 + slot];
        s.x += e.x; s.y += e.y; s.z += e.z; s.w += e.w;
    }
    __shared__ float4 part[4][32];
    part[rg][slot] = s;
    __syncthreads();
    if (rg == 0) {
        const float4 p0 = part[0][slot], p1 = part[1][slot], p2 = part[2][slot], p3 = part[3][slot];
        const float inv = 1.0f / fmaxf((float)cnt, 1e-6f);
        const float4 v = make_float4((p0.x + p1.x + p2.x + p3.x) * inv,
                                     (p0.y + p1.y + p2.y + p3.y) * inv,
                                     (p0.z + p1.z + p2.z + p3.z) * inv,
                                     (p0.w + p1.w + p2.w + p3.w) * inv);
        ((float4*)(centers + (size_t)c * D))[dchunk * 32 + slot] = v;
    }
}

// --- 4. d_neg_min: 8 rows per block, one thread per class (cc2 inline) ---
__global__ void k_dneg(const float* __restrict__ embn, const float* __restrict__ a2,
                       const int* __restrict__ t, const float* __restrict__ centers,
                       float* __restrict__ dneg, int n, const int* __restrict__ ncls) {
    const int C = *ncls;
    const int i0 = blockIdx.x * DROWS;
    __shared__ __align__(16) float lrow[DROWS][D];
    __shared__ float la2[DROWS];
    __shared__ int lt[DROWS];
    __shared__ float mins[DROWS][128];
#pragma unroll
    for (int r = 0; r < DROWS; ++r) {
        if (i0 + r < n)
            ((float4*)lrow[r])[threadIdx.x] =
                ((const float4*)(embn + (size_t)(i0 + r) * D))[threadIdx.x];
    }
    if (threadIdx.x < DROWS) {
        const int ii = i0 + (int)threadIdx.x;
        la2[threadIdx.x] = (ii < n) ? a2[ii] : 0.f;
        lt[threadIdx.x] = (ii < n) ? t[ii] : -1;
    }
    __syncthreads();
    const int c = threadIdx.x;
    float best[DROWS];
    if (c < C) {
        float acc[DROWS];
#pragma unroll
        for (int r = 0; r < DROWS; ++r) acc[r] = 0.f;
        float c2acc = 0.f;
        const float4* cp = (const float4*)(centers + (size_t)c * D);
        for (int k = 0; k < D4; ++k) {
            const float4 cv = cp[k];
            c2acc += dot4(cv, cv);
#pragma unroll
            for (int r = 0; r < DROWS; ++r) {
                const float4 ev = ((const float4*)lrow[r])[k];
                acc[r] += cv.x * ev.x + cv.y * ev.y + cv.z * ev.z + cv.w * ev.w;
            }
        }
#pragma unroll
        for (int r = 0; r < DROWS; ++r) {
            const float sq = la2[r] + c2acc - 2.f * acc[r];
            float dv = sqrtf(fmaxf(sq, FEPS));
            if (lt[r] == c) dv = FBIG;
            best[r] = dv;
        }
    } else {
#pragma unroll
        for (int r = 0; r < DROWS; ++r) best[r] = FBIG;
    }
#pragma unroll
    for (int r = 0; r < DROWS; ++r) mins[r][threadIdx.x] = best[r];
    __syncthreads();
    for (int s = 64; s > 0; s >>= 1) {
        if (threadIdx.x < s) {
#pragma unroll
            for (int r = 0; r < DROWS; ++r)
                mins[r][threadIdx.x] = fminf(mins[r][threadIdx.x], mins[r][threadIdx.x + s]);
        }
        __syncthreads();
    }
    if (threadIdx.x < DROWS && i0 + (int)threadIdx.x < n)
        dneg[i0 + threadIdx.x] = mins[threadIdx.x][0];
}

// --- 5. per-class Gram + top-3 hardest positives + d_pos ---
// grid (4 i-tiles x class), 256 threads as 8(ty) x 32(tx), 4x4 register tile.
// Inner loop holds only b0..b3 + one transient a (low VGPR liveness, no spills).
__global__ __launch_bounds__(256) void k_pos(
    const float* __restrict__ embn, const float* __restrict__ a2,
    const int* __restrict__ clist, const int* __restrict__ coff,
    const int* __restrict__ ccount, float* __restrict__ dpos,
    float* __restrict__ dvalid) {
    const int c = blockIdx.y;
    const int m = ccount[c];
    const int it0 = blockIdx.x * TI;
    if (m == 0 || it0 >= m) return;  // block-uniform
    const int off = coff[c];
    const int tid = threadIdx.x;
    const int tx = tid & 31;
    const int ty = tid >> 5;
    const int lane = tid & 63;
    const int wav = tid >> 6;

    __shared__ float4 At[8][TI];    // 4 KB per k-chunk (slot-major, transposed)
    __shared__ float4 Bt[8][TJ];    // 16 KB
    __shared__ int ig_s[TI];
    __shared__ float a2i_s[TI];
    __shared__ int jg_s[TJ];
    __shared__ float a2j_s[TJ];
    __shared__ int topj_s[TI][3];

    if (tid < TI) {
        const int gr = it0 + tid;
        const int gi = (gr < m) ? clist[off + gr] : -1;
        ig_s[tid] = gi;
        a2i_s[tid] = (gi >= 0) ? a2[gi] : 0.f;
    }

    float rv0[4], rv1[4], rv2[4];
    int rj0[4], rj1[4], rj2[4];
#pragma unroll
    for (int u = 0; u < 4; ++u) {
        rv0[u] = rv1[u] = rv2[u] = -FBIG;
        rj0[u] = rj1[u] = rj2[u] = -1;
    }

    for (int jb = 0; jb < m; jb += TJ) {
        __syncthreads();  // previous pass done with jg_s/a2j_s
        if (tid < TJ) {
            const int gr = jb + tid;
            const int gj = (gr < m) ? clist[off + gr] : -1;
            jg_s[tid] = gj;
            a2j_s[tid] = (gj >= 0) ? a2[gj] : 0.f;
        }
        float acc[4][4];
#pragma unroll
        for (int u = 0; u < 4; ++u)
#pragma unroll
            for (int v = 0; v < 4; ++v) acc[u][v] = 0.f;

        for (int kc4 = 0; kc4 < D4; kc4 += 8) {  // 16 k-chunks of 32 floats
            __syncthreads();  // previous chunk's compute done; metadata staged
            {   // stage A: 256 threads -> 32 rows x 8 slots
                const int arow = tid & 31, slot = tid >> 5;
                const int gi = ig_s[arow];
                float4 va = make_float4(0.f, 0.f, 0.f, 0.f);
                if (gi >= 0) va = ((const float4*)(embn + (size_t)gi * D))[kc4 + slot];
                At[slot][arow] = va;
            }
#pragma unroll
            for (int s = 0; s < 4; ++s) {  // stage B: 128 rows x 8 slots
                const int jrow = tid & 127;
                const int slot = (tid >> 7) + 2 * s;
                const int gj = jg_s[jrow];
                float4 vb = make_float4(0.f, 0.f, 0.f, 0.f);
                if (gj >= 0) vb = ((const float4*)(embn + (size_t)gj * D))[kc4 + slot];
                Bt[slot][jrow] = vb;
            }
            __syncthreads();
#pragma unroll
            for (int k4 = 0; k4 < 8; ++k4) {
                const float4 b0 = Bt[k4][tx];
                const float4 b1 = Bt[k4][tx + 32];
                const float4 b2 = Bt[k4][tx + 64];
                const float4 b3 = Bt[k4][tx + 96];
#pragma unroll
                for (int u = 0; u < 4; ++u) {
                    const float4 a = At[k4][ty + 8 * u];  // broadcast
                    acc[u][0] += dot4(a, b0);
                    acc[u][1] += dot4(a, b1);
                    acc[u][2] += dot4(a, b2);
                    acc[u][3] += dot4(a, b3);
                }
            }
        }
        // selection: per-thread running top3 per owned i-row
#pragma unroll
        for (int u = 0; u < 4; ++u) {
            const int iloc = ty + 8 * u;
            const int ig = ig_s[iloc];
            if (ig < 0) continue;
            const float a2i = a2i_s[iloc];
#pragma unroll
            for (int v = 0; v < 4; ++v) {
                const int jloc = tx + 32 * v;
                const int jg = jg_s[jloc];
                if (jg >= 0 && jg != ig) {
                    const float sq = a2i + a2j_s[jloc] - 2.f * acc[u][v];
                    ins3(sq, jg, rv0[u], rv1[u], rv2[u], rj0[u], rj1[u], rj2[u]);
                }
            }
        }
    }

    // butterfly merge across the 32 tx lanes (stays within half-wave)
#pragma unroll
    for (int o = 16; o > 0; o >>= 1) {
#pragma unroll
        for (int u = 0; u < 4; ++u) {
            const float ov0 = __shfl_xor(rv0[u], o); const int oj0 = __shfl_xor(rj0[u], o);
            const float ov1 = __shfl_xor(rv1[u], o); const int oj1 = __shfl_xor(rj1[u], o);
            const float ov2 = __shfl_xor(rv2[u], o); const int oj2 = __shfl_xor(rj2[u], o);
            ins3(ov0, oj0, rv0[u], rv1[u], rv2[u], rj0[u], rj1[u], rj2[u]);
            ins3(ov1, oj1, rv0[u], rv1[u], rv2[u], rj0[u], rj1[u], rj2[u]);
            ins3(ov2, oj2, rv0[u], rv1[u], rv2[u], rj0[u], rj1[u], rj2[u]);
        }
    }
    if (tx == 0) {
#pragma unroll
        for (int u = 0; u < 4; ++u) {
            const int iloc = ty + 8 * u;
            topj_s[iloc][0] = rj0[u]; topj_s[iloc][1] = rj1[u]; topj_s[iloc][2] = rj2[u];
        }
    }
    __syncthreads();

    // d_pos tail: 4 waves round-robin the 32 rows
    for (int rl = wav; rl < TI; rl += 4) {
        if (it0 + rl >= m) continue;
        const int i = ig_s[rl];
        const int j0 = topj_s[rl][0], j1 = topj_s[rl][1], j2 = topj_s[rl][2];
        const int nw = (j0 >= 0) + (j1 >= 0) + (j2 >= 0);
        if (nw > 0) {
            const int jA = j0;
            const int jB = (j1 >= 0) ? j1 : jA;
            const int jC = (j2 >= 0) ? j2 : jB;
            const float4* pi = (const float4*)(embn + (size_t)i * D);
            const float4* r0 = (const float4*)(embn + (size_t)jA * D);
            const float4* r1 = (const float4*)(embn + (size_t)jB * D);
            const float4* r2 = (const float4*)(embn + (size_t)jC * D);
            float accp = 0.f;
#pragma unroll
            for (int s = 0; s < 2; ++s) {
                const int k4 = lane + 64 * s;
                const float4 a = pi[k4];
                const float4 v0 = r0[k4], v1 = r1[k4], v2 = r2[k4];
                const float cx = (v0.x + v1.x + v2.x) * (1.f / 3.f);
                const float cy = (v0.y + v1.y + v2.y) * (1.f / 3.f);
                const float cz = (v0.z + v1.z + v2.z) * (1.f / 3.f);
                const float cw = (v0.w + v1.w + v2.w) * (1.f / 3.f);
                const float dx = a.x - cx, dy = a.y - cy, dz = a.z - cz, dw = a.w - cw;
                accp += dx * dx + dy * dy + dz * dz + dw * dw;
            }
            accp = wave_rsum_all(accp);
            if (lane == 0) { dpos[i] = sqrtf(fmaxf(accp, FEPS)); dvalid[i] = 1.f; }
        } else if (lane == 0) {
            dpos[i] = 0.f; dvalid[i] = 0.f;
        }
    }
}

// --- 6. stable softplus + masked mean ---
__global__ void k_loss(const float* __restrict__ dpos, const float* __restrict__ dneg,
                       const float* __restrict__ dvalid, float* __restrict__ accum, int n) {
    const int i = blockIdx.x * blockDim.x + threadIdx.x;
    float l = 0.f, v = 0.f;
    if (i < n) {
        v = dvalid[i];
        const float x = dpos[i] - dneg[i];
        const float sp = fmaxf(x, 0.f) + log1pf(expf(-fabsf(x)));
        l = sp * v;
    }
    l = wave_rsum(l);
    v = wave_rsum(v);
    __shared__ float wl[4], wv[4];
    const int lane = threadIdx.x & 63, w = threadIdx.x >> 6;
    if (lane == 0) { wl[w] = l; wv[w] = v; }
    __syncthreads();
    if (threadIdx.x == 0) {
        atomicAdd(&accum[0], wl[0] + wl[1] + wl[2] + wl[3]);
        atomicAdd(&accum[1], wv[0] + wv[1] + wv[2] + wv[3]);
    }
}

__global__ void k_final(const float* __restrict__ accum, float* __restrict__ out) {
    out[0] = accum[0] / fmaxf(accum[1], 1.0f);
}

extern "C" void kernel_launch(void* const* d_in, const int* in_sizes, int n_in,
                              void* d_out, int out_size, void* d_ws, size_t ws_size,
                              hipStream_t stream) {
    const float* emb = (const float*)d_in[0];
    const int* targets = (const int*)d_in[1];
    const int* ncls = (const int*)d_in[2];
    const int n = in_sizes[1];  // 8192

    float* fp = (float*)d_ws;
    float* embn = fp;    fp += (size_t)n * D;
    float* a2 = fp;      fp += n;
    float* centers = fp; fp += (size_t)MAXC * D;
    float* dneg = fp;    fp += n;
    float* dpos = fp;    fp += n;
    float* dvalid = fp;  fp += n;
    int* ccount = (int*)fp; fp += MAXC;
    float* accum = fp;   fp += 2;          // contiguous with ccount: one memset
    int* coff = (int*)fp;   fp += MAXC;
    int* clist = (int*)fp;  fp += n;

    hipMemsetAsync(ccount, 0, (MAXC + 2) * sizeof(int), stream);

    k_normalize<<<n, 128, 0, stream>>>(emb, targets, embn, a2, ccount);
    k_build<<<MAXC, 256, 0, stream>>>(targets, ccount, coff, clist, n, ncls);
    k_centers<<<dim3(4, MAXC), 128, 0, stream>>>(embn, clist, coff, ccount, centers);
    k_dneg<<<(n + DROWS - 1) / DROWS, 128, 0, stream>>>(embn, a2, targets, centers, dneg, n, ncls);
    k_pos<<<dim3(4, MAXC), 256, 0, stream>>>(embn, a2, clist, coff, ccount, dpos, dvalid);
    k_loss<<<(n + 255) / 256, 256, 0, stream>>>(dpos, dneg, dvalid, accum, n);
    k_final<<<1, 1, 0, stream>>>(accum, (float*)d_out);
}